// Round 5
// baseline (212.471 us; speedup 1.0000x reference)
//
#include <hip/hip_runtime.h>

#define N_NODES 50000
#define N_EDGES 800000
#define N_GRAPHS 512
#define FDIM 128
#define NTYPES_PAD 1000

constexpr int SCAN_TILE = 256;
constexpr int NB = (N_NODES + SCAN_TILE - 1) / SCAN_TILE;  // 196

typedef __bf16 bf16x8 __attribute__((ext_vector_type(8)));
typedef float f32x4 __attribute__((ext_vector_type(4)));
union BF8 { bf16x8 v; unsigned short u[8]; };

__device__ __forceinline__ unsigned short f2bf(float f) {
  unsigned int u = __float_as_uint(f);
  unsigned int r = (u + 0x7FFFu + ((u >> 16) & 1u)) >> 16;
  return (unsigned short)r;
}
__device__ __forceinline__ float bflo(unsigned int v) {
  return __uint_as_float(v << 16);
}
__device__ __forceinline__ float bfhi(unsigned int v) {
  return __uint_as_float(v & 0xFFFF0000u);
}

__global__ void k_init(int* __restrict__ cnt, int* __restrict__ fill,
                       float* __restrict__ Z, int* __restrict__ cnt_g) {
  int i = blockIdx.x * blockDim.x + threadIdx.x;  // 65536 threads
  if (i < N_NODES) { cnt[i] = 0; fill[i] = 0; }
  if (i < N_GRAPHS * FDIM) Z[i] = 0.0f;
  if (i < N_GRAPHS) cnt_g[i] = 0;
}

// edge in-degree count + (fused) batch histogram
__global__ void k_count(const int* __restrict__ dst, int* __restrict__ cnt,
                        const int* __restrict__ batch,
                        int* __restrict__ cnt_g) {
  int e = blockIdx.x * blockDim.x + threadIdx.x;
  if (e < N_EDGES) atomicAdd(&cnt[dst[e]], 1);
  if (e < N_NODES) atomicAdd(&cnt_g[batch[e]], 1);
}

__global__ void k_scan1(const int* __restrict__ cnt, int* __restrict__ row_ptr,
                        int* __restrict__ blk) {
  __shared__ int s[SCAN_TILE];
  int t = threadIdx.x;
  int i = blockIdx.x * SCAN_TILE + t;
  int v = (i < N_NODES) ? cnt[i] : 0;
  s[t] = v;
  __syncthreads();
  for (int d = 1; d < SCAN_TILE; d <<= 1) {
    int u = (t >= d) ? s[t - d] : 0;
    __syncthreads();
    s[t] += u;
    __syncthreads();
  }
  if (i < N_NODES) row_ptr[i] = s[t] - v;
  if (t == SCAN_TILE - 1) blk[blockIdx.x] = s[t];
}

__global__ void k_scan2(int* __restrict__ blk) {
  __shared__ int s[256];
  int t = threadIdx.x;
  int v = (t < NB) ? blk[t] : 0;
  s[t] = v;
  __syncthreads();
  for (int d = 1; d < 256; d <<= 1) {
    int u = (t >= d) ? s[t - d] : 0;
    __syncthreads();
    s[t] += u;
    __syncthreads();
  }
  if (t < NB) blk[t] = s[t] - v;
}

__global__ void k_scan3(const int* __restrict__ cnt, int* __restrict__ row_ptr,
                        const int* __restrict__ blk, float* __restrict__ dis) {
  int i = blockIdx.x * blockDim.x + threadIdx.x;
  if (i < N_NODES) {
    row_ptr[i] += blk[blockIdx.x];
    dis[i] = rsqrtf((float)(cnt[i] + 1));
  }
  if (i == 0) row_ptr[N_NODES] = N_EDGES;
}

// csr_t: (x_type[src], norm)  csr_s: (src, norm)
__global__ void k_fill(const int* __restrict__ src, const int* __restrict__ dst,
                       const int* __restrict__ x_type,
                       const int* __restrict__ row_ptr, int* __restrict__ fill,
                       const float* __restrict__ dis, int2* __restrict__ csr_t,
                       int2* __restrict__ csr_s) {
  int e = blockIdx.x * blockDim.x + threadIdx.x;
  if (e >= N_EDGES) return;
  int s = src[e], d = dst[e];
  int pos = row_ptr[d] + atomicAdd(&fill[d], 1);
  int nb = __float_as_int(dis[s] * dis[d]);
  csr_t[pos] = make_int2(x_type[s], nb);
  csr_s[pos] = make_int2(s, nb);
}

// W1 [128x128] f32 (k,n) -> Wt bf16 [n][k ^ ((n&15)<<3)]
__global__ void k_prep_w(const float* __restrict__ W,
                         unsigned short* __restrict__ Wt) {
  int id = blockIdx.x * blockDim.x + threadIdx.x;  // 16384
  int k = id >> 7, n = id & 127;
  Wt[n * 128 + (k ^ ((n & 15) << 3))] = f2bf(W[k * 128 + n]);
}

// T1 = emb @ W1  [1000 x 128] bf16. 4 waves/block, 64 rows/block.
__global__ __launch_bounds__(256) void k_embw(
    const float* __restrict__ emb, const unsigned short* __restrict__ Wt,
    unsigned short* __restrict__ T1) {
  __shared__ unsigned short Ws[128 * 128];
  int t = threadIdx.x, w = t >> 6, l = t & 63;
  {
    const float4* g = (const float4*)Wt;
    float4* ls = (float4*)Ws;
    for (int i = t; i < 2048; i += 256) ls[i] = g[i];
  }
  int row0 = blockIdx.x * 64 + w * 16;
  int arow = row0 + (l & 15);
  bool ok = arow < NTYPES_PAD;
  bf16x8 a[4];
#pragma unroll
  for (int ks = 0; ks < 4; ++ks) {
    BF8 av;
    const float* ap = emb + (size_t)arow * FDIM + (l >> 4) * 8 + ks * 32;
#pragma unroll
    for (int i = 0; i < 8; ++i) av.u[i] = ok ? f2bf(ap[i]) : 0;
    a[ks] = av.v;
  }
  __syncthreads();
  f32x4 acc[8] = {};
#pragma unroll
  for (int ks = 0; ks < 4; ++ks) {
#pragma unroll
    for (int ct = 0; ct < 8; ++ct) {
      int n = ct * 16 + (l & 15);
      int kk = (ks * 32 + (l >> 4) * 8) ^ ((n & 15) << 3);
      bf16x8 b = *(const bf16x8*)&Ws[n * 128 + kk];
      acc[ct] =
          __builtin_amdgcn_mfma_f32_16x16x32_bf16(a[ks], b, acc[ct], 0, 0, 0);
    }
  }
#pragma unroll
  for (int ct = 0; ct < 8; ++ct) {
    int col = ct * 16 + (l & 15);
#pragma unroll
    for (int r = 0; r < 4; ++r) {
      int row = row0 + (l >> 4) * 4 + r;
      if (row < NTYPES_PAD) T1[row * FDIM + col] = f2bf(acc[ct][r]);
    }
  }
}

// Layer-1 aggregate from L2-resident T1: 1 wave/node, 2 feats/lane.
__global__ void k_agg1(const int* __restrict__ x_type,
                       const unsigned short* __restrict__ T1,
                       const float* __restrict__ b1,
                       const int* __restrict__ row_ptr,
                       const int2* __restrict__ csr_t,
                       const float* __restrict__ dis,
                       unsigned int* __restrict__ y1) {
  int gid = blockIdx.x * blockDim.x + threadIdx.x;
  int node = gid >> 6;
  int lane = gid & 63;
  if (node >= N_NODES) return;
  const unsigned int* T = (const unsigned int*)T1;
  float di = dis[node];
  float w0 = di * di;
  unsigned int v = T[(size_t)x_type[node] * 64 + lane];
  float ax = bflo(v) * w0, ay = bfhi(v) * w0;
  int j = row_ptr[node], end = row_ptr[node + 1];
  for (; j + 4 <= end; j += 4) {
    int2 e0 = csr_t[j], e1 = csr_t[j + 1], e2 = csr_t[j + 2], e3 = csr_t[j + 3];
    unsigned int u0 = T[(size_t)e0.x * 64 + lane];
    unsigned int u1 = T[(size_t)e1.x * 64 + lane];
    unsigned int u2 = T[(size_t)e2.x * 64 + lane];
    unsigned int u3 = T[(size_t)e3.x * 64 + lane];
    float n0 = __int_as_float(e0.y), n1 = __int_as_float(e1.y);
    float n2 = __int_as_float(e2.y), n3 = __int_as_float(e3.y);
    ax = fmaf(bflo(u0), n0, ax); ay = fmaf(bfhi(u0), n0, ay);
    ax = fmaf(bflo(u1), n1, ax); ay = fmaf(bfhi(u1), n1, ay);
    ax = fmaf(bflo(u2), n2, ax); ay = fmaf(bfhi(u2), n2, ay);
    ax = fmaf(bflo(u3), n3, ax); ay = fmaf(bfhi(u3), n3, ay);
  }
  for (; j < end; ++j) {
    int2 e = csr_t[j];
    unsigned int u = T[(size_t)e.x * 64 + lane];
    float nw = __int_as_float(e.y);
    ax = fmaf(bflo(u), nw, ax);
    ay = fmaf(bfhi(u), nw, ay);
  }
  float2 bb = ((const float2*)b1)[lane];
  ax = fmaxf(ax + bb.x, 0.f);
  ay = fmaxf(ay + bb.y, 0.f);
  y1[(size_t)node * 64 + lane] = (unsigned int)f2bf(ax) |
                                 ((unsigned int)f2bf(ay) << 16);
}

// Pooled layer-2 aggregate: Z[g] = sum_{node in g} (d^2*y1[node] +
// sum_src norm*y1[src]). One wave per 8 consecutive nodes (batch sorted);
// register accumulation, atomic flush only on graph change.
#define NPW 8
__global__ void k_aggpool(const unsigned int* __restrict__ y1,
                          const int* __restrict__ row_ptr,
                          const int2* __restrict__ csr_s,
                          const float* __restrict__ dis,
                          const int* __restrict__ batch,
                          float* __restrict__ Z) {
  int gid = blockIdx.x * blockDim.x + threadIdx.x;
  int wid = gid >> 6;
  int lane = gid & 63;
  int n0 = wid * NPW;
  if (n0 >= N_NODES) return;
  int nend = min(n0 + NPW, N_NODES);
  float ax = 0.f, ay = 0.f;
  int gcur = batch[n0];
  for (int node = n0; node < nend; ++node) {
    int g = batch[node];
    if (g != gcur) {
      atomicAdd(&Z[(size_t)gcur * FDIM + 2 * lane], ax);
      atomicAdd(&Z[(size_t)gcur * FDIM + 2 * lane + 1], ay);
      ax = 0.f;
      ay = 0.f;
      gcur = g;
    }
    float di = dis[node];
    float w0 = di * di;
    unsigned int v = y1[(size_t)node * 64 + lane];
    float sx = bflo(v) * w0, sy = bfhi(v) * w0;
    int j = row_ptr[node], end = row_ptr[node + 1];
    for (; j + 4 <= end; j += 4) {
      int2 e0 = csr_s[j], e1 = csr_s[j + 1];
      int2 e2 = csr_s[j + 2], e3 = csr_s[j + 3];
      unsigned int u0 = y1[(size_t)e0.x * 64 + lane];
      unsigned int u1 = y1[(size_t)e1.x * 64 + lane];
      unsigned int u2 = y1[(size_t)e2.x * 64 + lane];
      unsigned int u3 = y1[(size_t)e3.x * 64 + lane];
      float n0_ = __int_as_float(e0.y), n1_ = __int_as_float(e1.y);
      float n2_ = __int_as_float(e2.y), n3_ = __int_as_float(e3.y);
      sx = fmaf(bflo(u0), n0_, sx); sy = fmaf(bfhi(u0), n0_, sy);
      sx = fmaf(bflo(u1), n1_, sx); sy = fmaf(bfhi(u1), n1_, sy);
      sx = fmaf(bflo(u2), n2_, sx); sy = fmaf(bfhi(u2), n2_, sy);
      sx = fmaf(bflo(u3), n3_, sx); sy = fmaf(bfhi(u3), n3_, sy);
    }
    for (; j < end; ++j) {
      int2 e = csr_s[j];
      unsigned int u = y1[(size_t)e.x * 64 + lane];
      float nw = __int_as_float(e.y);
      sx = fmaf(bflo(u), nw, sx);
      sy = fmaf(bfhi(u), nw, sy);
    }
    ax += sx;
    ay += sy;
  }
  atomicAdd(&Z[(size_t)gcur * FDIM + 2 * lane], ax);
  atomicAdd(&Z[(size_t)gcur * FDIM + 2 * lane + 1], ay);
}

// out[g] = Z[g] @ W2 + cnt_g[g]*b2. One block per graph, f32 exact.
__global__ __launch_bounds__(128) void k_zw2(const float* __restrict__ Z,
                                             const float* __restrict__ W2,
                                             const float* __restrict__ b2,
                                             const int* __restrict__ cnt_g,
                                             float* __restrict__ out) {
  __shared__ float Zs[FDIM];
  int g = blockIdx.x, t = threadIdx.x;
  Zs[t] = Z[(size_t)g * FDIM + t];
  __syncthreads();
  float acc = 0.f;
#pragma unroll 8
  for (int k = 0; k < FDIM; ++k) acc = fmaf(Zs[k], W2[k * FDIM + t], acc);
  out[(size_t)g * FDIM + t] = acc + (float)cnt_g[g] * b2[t];
}

extern "C" void kernel_launch(void* const* d_in, const int* in_sizes, int n_in,
                              void* d_out, int out_size, void* d_ws,
                              size_t ws_size, hipStream_t stream) {
  const int* x_type = (const int*)d_in[0];
  const int* edge_index = (const int*)d_in[1];
  const int* batch = (const int*)d_in[2];
  const float* emb = (const float*)d_in[3];
  const float* W1 = (const float*)d_in[4];
  const float* b1 = (const float*)d_in[5];
  const float* W2 = (const float*)d_in[6];
  const float* b2 = (const float*)d_in[7];
  float* out = (float*)d_out;

  const int* src = edge_index;
  const int* dst = edge_index + N_EDGES;

  char* p = (char*)d_ws;
  size_t off = 0;
  auto alloc = [&](size_t bytes) {
    void* r = p + off;
    off = (off + bytes + 255) & ~(size_t)255;
    return r;
  };
  float* dis = (float*)alloc(N_NODES * 4);
  int* cnt = (int*)alloc(N_NODES * 4);
  int* row_ptr = (int*)alloc((N_NODES + 1) * 4);
  int* fill = (int*)alloc(N_NODES * 4);
  int* blk = (int*)alloc(1024);
  int* cnt_g = (int*)alloc(N_GRAPHS * 4);
  int2* csr_t = (int2*)alloc((size_t)N_EDGES * 8);
  int2* csr_s = (int2*)alloc((size_t)N_EDGES * 8);
  unsigned short* Wt1 = (unsigned short*)alloc(128 * 128 * 2);
  unsigned short* T1 = (unsigned short*)alloc((size_t)NTYPES_PAD * FDIM * 2);
  unsigned int* y1 = (unsigned int*)alloc((size_t)N_NODES * 64 * 4);
  float* Z = (float*)alloc((size_t)N_GRAPHS * FDIM * 4);
  (void)ws_size;

  k_init<<<256, 256, 0, stream>>>(cnt, fill, Z, cnt_g);
  k_count<<<(N_EDGES + 255) / 256, 256, 0, stream>>>(dst, cnt, batch, cnt_g);
  k_scan1<<<NB, 256, 0, stream>>>(cnt, row_ptr, blk);
  k_scan2<<<1, 256, 0, stream>>>(blk);
  k_scan3<<<NB, 256, 0, stream>>>(cnt, row_ptr, blk, dis);
  k_fill<<<(N_EDGES + 255) / 256, 256, 0, stream>>>(src, dst, x_type, row_ptr,
                                                    fill, dis, csr_t, csr_s);
  k_prep_w<<<64, 256, 0, stream>>>(W1, Wt1);
  k_embw<<<(NTYPES_PAD + 63) / 64, 256, 0, stream>>>(emb, Wt1, T1);
  k_agg1<<<(N_NODES * 64 + 255) / 256, 256, 0, stream>>>(
      x_type, T1, b1, row_ptr, csr_t, dis, y1);
  int nwaves = (N_NODES + NPW - 1) / NPW;
  k_aggpool<<<(nwaves * 64 + 255) / 256, 256, 0, stream>>>(
      y1, row_ptr, csr_s, dis, batch, Z);
  k_zw2<<<N_GRAPHS, 128, 0, stream>>>(Z, W2, b2, cnt_g, out);
}

// Round 6
// 176.835 us; speedup vs baseline: 1.2015x; 1.2015x over previous
//
#include <hip/hip_runtime.h>

#define N_NODES 50000
#define N_EDGES 800000
#define N_GRAPHS 512
#define FDIM 128
#define NTYPES_PAD 1000

#define NBLK 128
#define CHUNK ((N_EDGES + NBLK - 1) / NBLK)  // 6250
#define NQUAD (N_NODES / 4)                  // 12500
#define NPAIR (N_NODES / 2)                  // 25000
#define NPW 8
#define NW ((N_NODES + NPW - 1) / NPW)       // 6250

constexpr int SCAN_TILE = 256;
constexpr int NB = (N_NODES + SCAN_TILE - 1) / SCAN_TILE;  // 196

typedef __bf16 bf16x8 __attribute__((ext_vector_type(8)));
typedef float f32x4 __attribute__((ext_vector_type(4)));
union BF8 { bf16x8 v; unsigned short u[8]; };

__device__ __forceinline__ unsigned short f2bf(float f) {
  unsigned int u = __float_as_uint(f);
  unsigned int r = (u + 0x7FFFu + ((u >> 16) & 1u)) >> 16;
  return (unsigned short)r;
}
__device__ __forceinline__ float bflo(unsigned int v) {
  return __uint_as_float(v << 16);
}
__device__ __forceinline__ float bfhi(unsigned int v) {
  return __uint_as_float(v & 0xFFFF0000u);
}

__global__ void k_init(float* __restrict__ Zb) {
  int i = blockIdx.x * blockDim.x + threadIdx.x;
  if (i < N_GRAPHS * FDIM) Zb[i] = 0.0f;
}

// Per-chunk LDS histogram (8-bit packed, 4 nodes/u32); emits per-edge local
// rank. No global atomics. Requires per-chunk per-node count < 256 (holds:
// max in-degree ~50 for this graph).
__global__ __launch_bounds__(512) void k_hist(const int* __restrict__ dst,
                                              unsigned int* __restrict__ Hist,
                                              unsigned char* __restrict__ rank8) {
  __shared__ unsigned int h[NQUAD];  // 50 KB
  int b = blockIdx.x, t = threadIdx.x;
  for (int i = t; i < NQUAD; i += 512) h[i] = 0;
  __syncthreads();
  int e0 = b * CHUNK, e1 = min(e0 + CHUNK, N_EDGES);
  for (int e = e0 + t; e < e1; e += 512) {
    int d = dst[e];
    unsigned int sh = (d & 3) * 8;
    unsigned int old = atomicAdd(&h[d >> 2], 1u << sh);
    rank8[e] = (unsigned char)((old >> sh) & 0xFFu);
  }
  __syncthreads();
  unsigned int* H = Hist + (size_t)b * NQUAD;
  for (int i = t; i < NQUAD; i += 512) H[i] = h[i];
}

// Column scan over blocks: per node, prefix over the 128 chunk-counts ->
// u16 base cursors (packed pairs), total cnt, dis.
__global__ void k_colscan(const unsigned int* __restrict__ Hist,
                          unsigned int* __restrict__ Cur, int* __restrict__ cnt,
                          float* __restrict__ dis) {
  int q = blockIdx.x * blockDim.x + threadIdx.x;
  if (q >= NQUAD) return;
  unsigned int r0 = 0, r1 = 0, r2 = 0, r3 = 0;
  for (int b = 0; b < NBLK; ++b) {
    unsigned int v = Hist[(size_t)b * NQUAD + q];
    Cur[(size_t)b * NPAIR + 2 * q] = r0 | (r1 << 16);
    Cur[(size_t)b * NPAIR + 2 * q + 1] = r2 | (r3 << 16);
    r0 += v & 255u;
    r1 += (v >> 8) & 255u;
    r2 += (v >> 16) & 255u;
    r3 += v >> 24;
  }
  int d = 4 * q;
  cnt[d] = r0; cnt[d + 1] = r1; cnt[d + 2] = r2; cnt[d + 3] = r3;
  dis[d] = rsqrtf((float)r0 + 1.f);
  dis[d + 1] = rsqrtf((float)r1 + 1.f);
  dis[d + 2] = rsqrtf((float)r2 + 1.f);
  dis[d + 3] = rsqrtf((float)r3 + 1.f);
}

__global__ void k_scan1(const int* __restrict__ cnt, int* __restrict__ row_ptr,
                        int* __restrict__ blk) {
  __shared__ int s[SCAN_TILE];
  int t = threadIdx.x;
  int i = blockIdx.x * SCAN_TILE + t;
  int v = (i < N_NODES) ? cnt[i] : 0;
  s[t] = v;
  __syncthreads();
  for (int d = 1; d < SCAN_TILE; d <<= 1) {
    int u = (t >= d) ? s[t - d] : 0;
    __syncthreads();
    s[t] += u;
    __syncthreads();
  }
  if (i < N_NODES) row_ptr[i] = s[t] - v;
  if (t == SCAN_TILE - 1) blk[blockIdx.x] = s[t];
}

__global__ void k_scan2(int* __restrict__ blk) {
  __shared__ int s[256];
  int t = threadIdx.x;
  int v = (t < NB) ? blk[t] : 0;
  s[t] = v;
  __syncthreads();
  for (int d = 1; d < 256; d <<= 1) {
    int u = (t >= d) ? s[t - d] : 0;
    __syncthreads();
    s[t] += u;
    __syncthreads();
  }
  if (t < NB) blk[t] = s[t] - v;
}

__global__ void k_scan3(int* __restrict__ row_ptr, const int* __restrict__ blk) {
  int i = blockIdx.x * blockDim.x + threadIdx.x;
  if (i < N_NODES) row_ptr[i] += blk[blockIdx.x];
  if (i == 0) row_ptr[N_NODES] = N_EDGES;
}

// CSR fill, no atomics: pos = row_ptr[d] + base[b][d] + rank8[e].
__global__ __launch_bounds__(512) void k_fill2(
    const int* __restrict__ src, const int* __restrict__ dst,
    const int* __restrict__ x_type, const int* __restrict__ row_ptr,
    const unsigned int* __restrict__ Cur, const unsigned char* __restrict__ rank8,
    const float* __restrict__ dis, int2* __restrict__ csr_t,
    int2* __restrict__ csr_s) {
  int e = blockIdx.x * blockDim.x + threadIdx.x;
  if (e >= N_EDGES) return;
  int b = e / CHUNK;
  int s = src[e], d = dst[e];
  unsigned int cw = Cur[(size_t)b * NPAIR + (d >> 1)];
  int base = (int)((cw >> ((d & 1) * 16)) & 0xFFFFu);
  int pos = row_ptr[d] + base + (int)rank8[e];
  int nb = __float_as_int(dis[s] * dis[d]);
  csr_t[pos] = make_int2(x_type[s], nb);
  csr_s[pos] = make_int2(s, nb);
}

// graph start offsets from sorted batch (gstart[N_GRAPHS] = N_NODES)
__global__ void k_gstart(const int* __restrict__ batch,
                         int* __restrict__ gstart) {
  int i = blockIdx.x * blockDim.x + threadIdx.x;
  if (i >= N_NODES) return;
  int b = batch[i];
  int prev = (i == 0) ? -1 : batch[i - 1];
  for (int g = prev + 1; g <= b; ++g) gstart[g] = i;
  if (i == N_NODES - 1)
    for (int g = b + 1; g <= N_GRAPHS; ++g) gstart[g] = N_NODES;
}

// W1 [128x128] f32 (k,n) -> Wt bf16 [n][k ^ ((n&15)<<3)]
__global__ void k_prep_w(const float* __restrict__ W,
                         unsigned short* __restrict__ Wt) {
  int id = blockIdx.x * blockDim.x + threadIdx.x;  // 16384
  int k = id >> 7, n = id & 127;
  Wt[n * 128 + (k ^ ((n & 15) << 3))] = f2bf(W[k * 128 + n]);
}

// T1 = emb @ W1  [1000 x 128] bf16.
__global__ __launch_bounds__(256) void k_embw(
    const float* __restrict__ emb, const unsigned short* __restrict__ Wt,
    unsigned short* __restrict__ T1) {
  __shared__ unsigned short Ws[128 * 128];
  int t = threadIdx.x, w = t >> 6, l = t & 63;
  {
    const float4* g = (const float4*)Wt;
    float4* ls = (float4*)Ws;
    for (int i = t; i < 2048; i += 256) ls[i] = g[i];
  }
  int row0 = blockIdx.x * 64 + w * 16;
  int arow = row0 + (l & 15);
  bool ok = arow < NTYPES_PAD;
  bf16x8 a[4];
#pragma unroll
  for (int ks = 0; ks < 4; ++ks) {
    BF8 av;
    const float* ap = emb + (size_t)arow * FDIM + (l >> 4) * 8 + ks * 32;
#pragma unroll
    for (int i = 0; i < 8; ++i) av.u[i] = ok ? f2bf(ap[i]) : 0;
    a[ks] = av.v;
  }
  __syncthreads();
  f32x4 acc[8] = {};
#pragma unroll
  for (int ks = 0; ks < 4; ++ks) {
#pragma unroll
    for (int ct = 0; ct < 8; ++ct) {
      int n = ct * 16 + (l & 15);
      int kk = (ks * 32 + (l >> 4) * 8) ^ ((n & 15) << 3);
      bf16x8 b = *(const bf16x8*)&Ws[n * 128 + kk];
      acc[ct] =
          __builtin_amdgcn_mfma_f32_16x16x32_bf16(a[ks], b, acc[ct], 0, 0, 0);
    }
  }
#pragma unroll
  for (int ct = 0; ct < 8; ++ct) {
    int col = ct * 16 + (l & 15);
#pragma unroll
    for (int r = 0; r < 4; ++r) {
      int row = row0 + (l >> 4) * 4 + r;
      if (row < NTYPES_PAD) T1[row * FDIM + col] = f2bf(acc[ct][r]);
    }
  }
}

// Layer-1 aggregate from L2-resident T1: 1 wave/node, 2 feats/lane.
__global__ void k_agg1(const int* __restrict__ x_type,
                       const unsigned short* __restrict__ T1,
                       const float* __restrict__ b1,
                       const int* __restrict__ row_ptr,
                       const int2* __restrict__ csr_t,
                       const float* __restrict__ dis,
                       unsigned int* __restrict__ y1) {
  int gid = blockIdx.x * blockDim.x + threadIdx.x;
  int node = gid >> 6;
  int lane = gid & 63;
  if (node >= N_NODES) return;
  const unsigned int* T = (const unsigned int*)T1;
  float di = dis[node];
  float w0 = di * di;
  unsigned int v = T[(size_t)x_type[node] * 64 + lane];
  float ax = bflo(v) * w0, ay = bfhi(v) * w0;
  int j = row_ptr[node], end = row_ptr[node + 1];
  for (; j + 4 <= end; j += 4) {
    int2 e0 = csr_t[j], e1 = csr_t[j + 1], e2 = csr_t[j + 2], e3 = csr_t[j + 3];
    unsigned int u0 = T[(size_t)e0.x * 64 + lane];
    unsigned int u1 = T[(size_t)e1.x * 64 + lane];
    unsigned int u2 = T[(size_t)e2.x * 64 + lane];
    unsigned int u3 = T[(size_t)e3.x * 64 + lane];
    float n0 = __int_as_float(e0.y), n1 = __int_as_float(e1.y);
    float n2 = __int_as_float(e2.y), n3 = __int_as_float(e3.y);
    ax = fmaf(bflo(u0), n0, ax); ay = fmaf(bfhi(u0), n0, ay);
    ax = fmaf(bflo(u1), n1, ax); ay = fmaf(bfhi(u1), n1, ay);
    ax = fmaf(bflo(u2), n2, ax); ay = fmaf(bfhi(u2), n2, ay);
    ax = fmaf(bflo(u3), n3, ax); ay = fmaf(bfhi(u3), n3, ay);
  }
  for (; j < end; ++j) {
    int2 e = csr_t[j];
    unsigned int u = T[(size_t)e.x * 64 + lane];
    float nw = __int_as_float(e.y);
    ax = fmaf(bflo(u), nw, ax);
    ay = fmaf(bfhi(u), nw, ay);
  }
  float2 bb = ((const float2*)b1)[lane];
  ax = fmaxf(ax + bb.x, 0.f);
  ay = fmaxf(ay + bb.y, 0.f);
  y1[(size_t)node * 64 + lane] = (unsigned int)f2bf(ax) |
                                 ((unsigned int)f2bf(ay) << 16);
}

// Pooled layer-2 aggregate: one wave per NPW consecutive nodes. First-graph
// segment -> Partials row (no atomics); later segments (rare) -> Zb atomics.
__global__ void k_aggpool(const unsigned int* __restrict__ y1,
                          const int* __restrict__ row_ptr,
                          const int2* __restrict__ csr_s,
                          const float* __restrict__ dis,
                          const int* __restrict__ batch,
                          float* __restrict__ Partials, int* __restrict__ Gid,
                          float* __restrict__ Zb) {
  int gid = blockIdx.x * blockDim.x + threadIdx.x;
  int wid = gid >> 6;
  int lane = gid & 63;
  int n0 = wid * NPW;
  if (n0 >= N_NODES) return;
  int nend = min(n0 + NPW, N_NODES);
  int g0 = batch[n0];
  int gcur = g0;
  float px = 0.f, py = 0.f;
  float ax = 0.f, ay = 0.f;
  for (int node = n0; node < nend; ++node) {
    int g = batch[node];
    if (g != gcur) {
      if (gcur == g0) {
        px = ax; py = ay;
      } else {
        atomicAdd(&Zb[(size_t)gcur * FDIM + 2 * lane], ax);
        atomicAdd(&Zb[(size_t)gcur * FDIM + 2 * lane + 1], ay);
      }
      ax = 0.f; ay = 0.f;
      gcur = g;
    }
    float di = dis[node];
    float w0 = di * di;
    unsigned int v = y1[(size_t)node * 64 + lane];
    float sx = bflo(v) * w0, sy = bfhi(v) * w0;
    int j = row_ptr[node], end = row_ptr[node + 1];
    for (; j + 4 <= end; j += 4) {
      int2 e0 = csr_s[j], e1 = csr_s[j + 1];
      int2 e2 = csr_s[j + 2], e3 = csr_s[j + 3];
      unsigned int u0 = y1[(size_t)e0.x * 64 + lane];
      unsigned int u1 = y1[(size_t)e1.x * 64 + lane];
      unsigned int u2 = y1[(size_t)e2.x * 64 + lane];
      unsigned int u3 = y1[(size_t)e3.x * 64 + lane];
      float n0_ = __int_as_float(e0.y), n1_ = __int_as_float(e1.y);
      float n2_ = __int_as_float(e2.y), n3_ = __int_as_float(e3.y);
      sx = fmaf(bflo(u0), n0_, sx); sy = fmaf(bfhi(u0), n0_, sy);
      sx = fmaf(bflo(u1), n1_, sx); sy = fmaf(bfhi(u1), n1_, sy);
      sx = fmaf(bflo(u2), n2_, sx); sy = fmaf(bfhi(u2), n2_, sy);
      sx = fmaf(bflo(u3), n3_, sx); sy = fmaf(bfhi(u3), n3_, sy);
    }
    for (; j < end; ++j) {
      int2 e = csr_s[j];
      unsigned int u = y1[(size_t)e.x * 64 + lane];
      float nw = __int_as_float(e.y);
      sx = fmaf(bflo(u), nw, sx);
      sy = fmaf(bfhi(u), nw, sy);
    }
    ax += sx;
    ay += sy;
  }
  if (gcur == g0) {
    px = ax; py = ay;
  } else {
    atomicAdd(&Zb[(size_t)gcur * FDIM + 2 * lane], ax);
    atomicAdd(&Zb[(size_t)gcur * FDIM + 2 * lane + 1], ay);
  }
  ((float2*)Partials)[(size_t)wid * 64 + lane] = make_float2(px, py);
  if (lane == 0) Gid[wid] = g0;
}

// Reduce partials + Zb -> Z[g], then out[g] = Z@W2 + nodecount*b2.
__global__ __launch_bounds__(128) void k_poolzw2(
    const float* __restrict__ Partials, const int* __restrict__ Gid,
    const float* __restrict__ Zb, const int* __restrict__ gstart,
    const float* __restrict__ W2, const float* __restrict__ b2,
    float* __restrict__ out) {
  __shared__ float Zs[FDIM];
  int g = blockIdx.x, t = threadIdx.x;
  int s = gstart[g], e = gstart[g + 1];
  float acc = Zb[(size_t)g * FDIM + t];
  if (e > s) {
    int w0 = s / NPW, w1 = (e - 1) / NPW;
    for (int w = w0; w <= w1; ++w)
      if (Gid[w] == g) acc += Partials[(size_t)w * FDIM + t];
  }
  Zs[t] = acc;
  __syncthreads();
  float o = 0.f;
#pragma unroll 8
  for (int k = 0; k < FDIM; ++k) o = fmaf(Zs[k], W2[k * FDIM + t], o);
  out[(size_t)g * FDIM + t] = o + (float)(e - s) * b2[t];
}

extern "C" void kernel_launch(void* const* d_in, const int* in_sizes, int n_in,
                              void* d_out, int out_size, void* d_ws,
                              size_t ws_size, hipStream_t stream) {
  const int* x_type = (const int*)d_in[0];
  const int* edge_index = (const int*)d_in[1];
  const int* batch = (const int*)d_in[2];
  const float* emb = (const float*)d_in[3];
  const float* W1 = (const float*)d_in[4];
  const float* b1 = (const float*)d_in[5];
  const float* W2 = (const float*)d_in[6];
  const float* b2 = (const float*)d_in[7];
  float* out = (float*)d_out;

  const int* src = edge_index;
  const int* dst = edge_index + N_EDGES;

  char* p = (char*)d_ws;
  size_t off = 0;
  auto alloc = [&](size_t bytes) {
    void* r = p + off;
    off = (off + bytes + 255) & ~(size_t)255;
    return r;
  };
  float* dis = (float*)alloc(N_NODES * 4);
  int* cnt = (int*)alloc(N_NODES * 4);
  int* row_ptr = (int*)alloc((N_NODES + 1) * 4);
  int* blk = (int*)alloc(1024);
  int* gstart = (int*)alloc((N_GRAPHS + 1) * 4);
  unsigned int* Hist = (unsigned int*)alloc((size_t)NBLK * NQUAD * 4);
  unsigned int* Cur = (unsigned int*)alloc((size_t)NBLK * NPAIR * 4);
  unsigned char* rank8 = (unsigned char*)alloc(N_EDGES);
  int2* csr_t = (int2*)alloc((size_t)N_EDGES * 8);
  int2* csr_s = (int2*)alloc((size_t)N_EDGES * 8);
  unsigned short* Wt1 = (unsigned short*)alloc(128 * 128 * 2);
  unsigned short* T1 = (unsigned short*)alloc((size_t)NTYPES_PAD * FDIM * 2);
  unsigned int* y1 = (unsigned int*)alloc((size_t)N_NODES * 64 * 4);
  float* Partials = (float*)alloc((size_t)NW * FDIM * 4);
  int* Gid = (int*)alloc(NW * 4);
  float* Zb = (float*)alloc((size_t)N_GRAPHS * FDIM * 4);
  (void)ws_size;

  k_init<<<256, 256, 0, stream>>>(Zb);
  k_hist<<<NBLK, 512, 0, stream>>>(dst, Hist, rank8);
  k_colscan<<<(NQUAD + 255) / 256, 256, 0, stream>>>(Hist, Cur, cnt, dis);
  k_scan1<<<NB, 256, 0, stream>>>(cnt, row_ptr, blk);
  k_scan2<<<1, 256, 0, stream>>>(blk);
  k_scan3<<<NB, 256, 0, stream>>>(row_ptr, blk);
  k_fill2<<<(N_EDGES + 511) / 512, 512, 0, stream>>>(
      src, dst, x_type, row_ptr, Cur, rank8, dis, csr_t, csr_s);
  k_gstart<<<(N_NODES + 255) / 256, 256, 0, stream>>>(batch, gstart);
  k_prep_w<<<64, 256, 0, stream>>>(W1, Wt1);
  k_embw<<<(NTYPES_PAD + 63) / 64, 256, 0, stream>>>(emb, Wt1, T1);
  k_agg1<<<(N_NODES * 64 + 255) / 256, 256, 0, stream>>>(
      x_type, T1, b1, row_ptr, csr_t, dis, y1);
  k_aggpool<<<(NW * 64 + 255) / 256, 256, 0, stream>>>(
      y1, row_ptr, csr_s, dis, batch, Partials, Gid, Zb);
  k_poolzw2<<<N_GRAPHS, 128, 0, stream>>>(Partials, Gid, Zb, gstart, W2, b2,
                                          out);
}

// Round 7
// 169.286 us; speedup vs baseline: 1.2551x; 1.0446x over previous
//
#include <hip/hip_runtime.h>

#define N_NODES 50000
#define N_EDGES 800000
#define N_GRAPHS 512
#define FDIM 128
#define NTYPES_PAD 1000

#define NBLK 128
#define CHUNK ((N_EDGES + NBLK - 1) / NBLK)  // 6250
#define NQUAD (N_NODES / 4)                  // 12500
#define NPW 4
#define NW ((N_NODES + NPW - 1) / NPW)       // 12500

constexpr int SCAN_TILE = 256;
constexpr int NB = (N_NODES + SCAN_TILE - 1) / SCAN_TILE;  // 196

typedef __bf16 bf16x8 __attribute__((ext_vector_type(8)));
typedef float f32x4 __attribute__((ext_vector_type(4)));
union BF8 { bf16x8 v; unsigned short u[8]; };

__device__ __forceinline__ unsigned short f2bf(float f) {
  unsigned int u = __float_as_uint(f);
  unsigned int r = (u + 0x7FFFu + ((u >> 16) & 1u)) >> 16;
  return (unsigned short)r;
}
__device__ __forceinline__ float bflo(unsigned int v) {
  return __uint_as_float(v << 16);
}
__device__ __forceinline__ float bfhi(unsigned int v) {
  return __uint_as_float(v & 0xFFFF0000u);
}

// zero Zb + graph start offsets (batch sorted). 256x256 = 65536 threads.
__global__ void k_misc(float* __restrict__ Zb, const int* __restrict__ batch,
                       int* __restrict__ gstart) {
  int i = blockIdx.x * blockDim.x + threadIdx.x;
  if (i < N_GRAPHS * FDIM) Zb[i] = 0.0f;
  if (i >= N_NODES) return;
  int b = batch[i];
  int prev = (i == 0) ? -1 : batch[i - 1];
  for (int g = prev + 1; g <= b; ++g) gstart[g] = i;
  if (i == N_NODES - 1)
    for (int g = b + 1; g <= N_GRAPHS; ++g) gstart[g] = N_NODES;
}

// Per-chunk LDS histogram (8-bit packed); emits per-edge local rank.
__global__ __launch_bounds__(512) void k_hist(const int* __restrict__ dst,
                                              unsigned int* __restrict__ Hist,
                                              unsigned char* __restrict__ rank8) {
  __shared__ unsigned int h[NQUAD];  // 50 KB
  int b = blockIdx.x, t = threadIdx.x;
  for (int i = t; i < NQUAD; i += 512) h[i] = 0;
  __syncthreads();
  int e0 = b * CHUNK, e1 = min(e0 + CHUNK, N_EDGES);
  for (int e = e0 + t; e < e1; e += 512) {
    int d = dst[e];
    unsigned int sh = (d & 3) * 8;
    unsigned int old = atomicAdd(&h[d >> 2], 1u << sh);
    rank8[e] = (unsigned char)((old >> sh) & 0xFFu);
  }
  __syncthreads();
  unsigned int* H = Hist + (size_t)b * NQUAD;
  for (int i = t; i < NQUAD; i += 512) H[i] = h[i];
}

// Per node: prefix over 128 chunk-counts -> u8 base cursors (packed u32),
// total cnt, dis, nodeinfo = type | cnt<<16.
__global__ void k_colscan(const unsigned int* __restrict__ Hist,
                          const int* __restrict__ x_type,
                          unsigned int* __restrict__ Cur, int* __restrict__ cnt,
                          float* __restrict__ dis,
                          unsigned int* __restrict__ nodeinfo) {
  int q = blockIdx.x * blockDim.x + threadIdx.x;
  if (q >= NQUAD) return;
  unsigned int r0 = 0, r1 = 0, r2 = 0, r3 = 0;
  for (int b = 0; b < NBLK; ++b) {
    unsigned int v = Hist[(size_t)b * NQUAD + q];
    Cur[(size_t)b * NQUAD + q] =
        (r0 & 255u) | ((r1 & 255u) << 8) | ((r2 & 255u) << 16) | (r3 << 24);
    r0 += v & 255u;
    r1 += (v >> 8) & 255u;
    r2 += (v >> 16) & 255u;
    r3 += v >> 24;
  }
  int d = 4 * q;
  ((int4*)cnt)[q] = make_int4(r0, r1, r2, r3);
  float4 dv = make_float4(rsqrtf((float)r0 + 1.f), rsqrtf((float)r1 + 1.f),
                          rsqrtf((float)r2 + 1.f), rsqrtf((float)r3 + 1.f));
  ((float4*)dis)[q] = dv;
  int4 xt = ((const int4*)x_type)[q];
  ((uint4*)nodeinfo)[q] =
      make_uint4((unsigned int)xt.x | (r0 << 16), (unsigned int)xt.y | (r1 << 16),
                 (unsigned int)xt.z | (r2 << 16), (unsigned int)xt.w | (r3 << 16));
}

__global__ void k_scan1(const int* __restrict__ cnt, int* __restrict__ row_ptr,
                        int* __restrict__ blk) {
  __shared__ int s[SCAN_TILE];
  int t = threadIdx.x;
  int i = blockIdx.x * SCAN_TILE + t;
  int v = (i < N_NODES) ? cnt[i] : 0;
  s[t] = v;
  __syncthreads();
  for (int d = 1; d < SCAN_TILE; d <<= 1) {
    int u = (t >= d) ? s[t - d] : 0;
    __syncthreads();
    s[t] += u;
    __syncthreads();
  }
  if (i < N_NODES) row_ptr[i] = s[t] - v;
  if (t == SCAN_TILE - 1) blk[blockIdx.x] = s[t];
}

__global__ void k_scan2(int* __restrict__ blk) {
  __shared__ int s[256];
  int t = threadIdx.x;
  int v = (t < NB) ? blk[t] : 0;
  s[t] = v;
  __syncthreads();
  for (int d = 1; d < 256; d <<= 1) {
    int u = (t >= d) ? s[t - d] : 0;
    __syncthreads();
    s[t] += u;
    __syncthreads();
  }
  if (t < NB) blk[t] = s[t] - v;
}

__global__ void k_scan3(int* __restrict__ row_ptr, const int* __restrict__ blk) {
  int i = blockIdx.x * blockDim.x + threadIdx.x;
  if (i < N_NODES) row_ptr[i] += blk[blockIdx.x];
  if (i == 0) row_ptr[N_NODES] = N_EDGES;
}

// CSR fill, no atomics. csr1 = nodeinfo[s]; csr2 = (u16)s.
__global__ __launch_bounds__(512) void k_fill2(
    const int* __restrict__ src, const int* __restrict__ dst,
    const int* __restrict__ row_ptr, const unsigned int* __restrict__ Cur,
    const unsigned char* __restrict__ rank8,
    const unsigned int* __restrict__ nodeinfo, unsigned int* __restrict__ csr1,
    unsigned short* __restrict__ csr2) {
  int e = blockIdx.x * blockDim.x + threadIdx.x;
  if (e >= N_EDGES) return;
  int b = e / CHUNK;
  int s = src[e], d = dst[e];
  unsigned int cw = Cur[(size_t)b * NQUAD + (d >> 2)];
  int base = (int)((cw >> ((d & 3) * 8)) & 0xFFu);
  int pos = row_ptr[d] + base + (int)rank8[e];
  csr1[pos] = nodeinfo[s];
  csr2[pos] = (unsigned short)s;
}

// T1 = emb @ W1 [1000x128] bf16; converts W1 f32->swizzled bf16 LDS in-block.
__global__ __launch_bounds__(256) void k_embw(
    const float* __restrict__ emb, const float* __restrict__ W1,
    unsigned short* __restrict__ T1) {
  __shared__ unsigned short Ws[128 * 128];
  int t = threadIdx.x, w = t >> 6, l = t & 63;
  for (int i = t; i < 16384; i += 256) {
    int k = i >> 7, n = i & 127;
    Ws[n * 128 + (k ^ ((n & 15) << 3))] = f2bf(W1[i]);
  }
  int row0 = blockIdx.x * 64 + w * 16;
  int arow = row0 + (l & 15);
  bool ok = arow < NTYPES_PAD;
  bf16x8 a[4];
#pragma unroll
  for (int ks = 0; ks < 4; ++ks) {
    BF8 av;
    const float* ap = emb + (size_t)arow * FDIM + (l >> 4) * 8 + ks * 32;
#pragma unroll
    for (int i = 0; i < 8; ++i) av.u[i] = ok ? f2bf(ap[i]) : 0;
    a[ks] = av.v;
  }
  __syncthreads();
  f32x4 acc[8] = {};
#pragma unroll
  for (int ks = 0; ks < 4; ++ks) {
#pragma unroll
    for (int ct = 0; ct < 8; ++ct) {
      int n = ct * 16 + (l & 15);
      int kk = (ks * 32 + (l >> 4) * 8) ^ ((n & 15) << 3);
      bf16x8 b = *(const bf16x8*)&Ws[n * 128 + kk];
      acc[ct] =
          __builtin_amdgcn_mfma_f32_16x16x32_bf16(a[ks], b, acc[ct], 0, 0, 0);
    }
  }
#pragma unroll
  for (int ct = 0; ct < 8; ++ct) {
    int col = ct * 16 + (l & 15);
#pragma unroll
    for (int r = 0; r < 4; ++r) {
      int row = row0 + (l >> 4) * 4 + r;
      if (row < NTYPES_PAD) T1[row * FDIM + col] = f2bf(acc[ct][r]);
    }
  }
}

// Layer 1: S = di*T1[type_d] + sum_e rsqrt(cnt_s+1)*T1[type_s];
// ytilde = di * relu(di*S + b1). 1 wave/node.
__global__ void k_agg1(const unsigned int* __restrict__ nodeinfo,
                       const unsigned short* __restrict__ T1,
                       const float* __restrict__ b1,
                       const int* __restrict__ row_ptr,
                       const unsigned int* __restrict__ csr1,
                       const float* __restrict__ dis,
                       unsigned int* __restrict__ y1) {
  int gid = blockIdx.x * blockDim.x + threadIdx.x;
  int node = gid >> 6;
  int lane = gid & 63;
  if (node >= N_NODES) return;
  const unsigned int* T = (const unsigned int*)T1;
  float di = dis[node];
  unsigned int ni = nodeinfo[node];
  unsigned int v = T[(size_t)(ni & 0xFFFFu) * 64 + lane];
  float ax = bflo(v) * di, ay = bfhi(v) * di;
  int j = row_ptr[node], end = row_ptr[node + 1];
  for (; j + 4 <= end; j += 4) {
    unsigned int e0 = csr1[j], e1 = csr1[j + 1];
    unsigned int e2 = csr1[j + 2], e3 = csr1[j + 3];
    unsigned int u0 = T[(size_t)(e0 & 0xFFFFu) * 64 + lane];
    unsigned int u1 = T[(size_t)(e1 & 0xFFFFu) * 64 + lane];
    unsigned int u2 = T[(size_t)(e2 & 0xFFFFu) * 64 + lane];
    unsigned int u3 = T[(size_t)(e3 & 0xFFFFu) * 64 + lane];
    float n0 = rsqrtf((float)(e0 >> 16) + 1.f);
    float n1 = rsqrtf((float)(e1 >> 16) + 1.f);
    float n2 = rsqrtf((float)(e2 >> 16) + 1.f);
    float n3 = rsqrtf((float)(e3 >> 16) + 1.f);
    ax = fmaf(bflo(u0), n0, ax); ay = fmaf(bfhi(u0), n0, ay);
    ax = fmaf(bflo(u1), n1, ax); ay = fmaf(bfhi(u1), n1, ay);
    ax = fmaf(bflo(u2), n2, ax); ay = fmaf(bfhi(u2), n2, ay);
    ax = fmaf(bflo(u3), n3, ax); ay = fmaf(bfhi(u3), n3, ay);
  }
  for (; j < end; ++j) {
    unsigned int e = csr1[j];
    unsigned int u = T[(size_t)(e & 0xFFFFu) * 64 + lane];
    float nw = rsqrtf((float)(e >> 16) + 1.f);
    ax = fmaf(bflo(u), nw, ax);
    ay = fmaf(bfhi(u), nw, ay);
  }
  float2 bb = ((const float2*)b1)[lane];
  ax = fmaxf(fmaf(di, ax, bb.x), 0.f) * di;
  ay = fmaxf(fmaf(di, ay, bb.y), 0.f) * di;
  y1[(size_t)node * 64 + lane] = (unsigned int)f2bf(ax) |
                                 ((unsigned int)f2bf(ay) << 16);
}

// Pooled layer 2 over pre-scaled ytilde: per node s = ytilde[d] +
// sum ytilde[src]; pool += di*s. One wave per NPW nodes; edge weights = 1.
__global__ void k_aggpool(const unsigned int* __restrict__ y1,
                          const int* __restrict__ row_ptr,
                          const unsigned short* __restrict__ csr2,
                          const float* __restrict__ dis,
                          const int* __restrict__ batch,
                          float* __restrict__ Partials, int* __restrict__ Gid,
                          float* __restrict__ Zb) {
  int gid = blockIdx.x * blockDim.x + threadIdx.x;
  int wid = gid >> 6;
  int lane = gid & 63;
  int n0 = wid * NPW;
  if (n0 >= N_NODES) return;
  int nend = min(n0 + NPW, N_NODES);
  int g0 = batch[n0];
  int gcur = g0;
  float px = 0.f, py = 0.f;
  float ax = 0.f, ay = 0.f;
  for (int node = n0; node < nend; ++node) {
    int g = batch[node];
    if (g != gcur) {
      if (gcur == g0) {
        px = ax; py = ay;
      } else {
        atomicAdd(&Zb[(size_t)gcur * FDIM + 2 * lane], ax);
        atomicAdd(&Zb[(size_t)gcur * FDIM + 2 * lane + 1], ay);
      }
      ax = 0.f; ay = 0.f;
      gcur = g;
    }
    float di = dis[node];
    unsigned int v = y1[(size_t)node * 64 + lane];
    float sx = bflo(v), sy = bfhi(v);
    int j = row_ptr[node], end = row_ptr[node + 1];
    for (; j + 4 <= end; j += 4) {
      int s0 = csr2[j], s1 = csr2[j + 1], s2 = csr2[j + 2], s3 = csr2[j + 3];
      unsigned int u0 = y1[(size_t)s0 * 64 + lane];
      unsigned int u1 = y1[(size_t)s1 * 64 + lane];
      unsigned int u2 = y1[(size_t)s2 * 64 + lane];
      unsigned int u3 = y1[(size_t)s3 * 64 + lane];
      sx += bflo(u0) + bflo(u1) + bflo(u2) + bflo(u3);
      sy += bfhi(u0) + bfhi(u1) + bfhi(u2) + bfhi(u3);
    }
    for (; j < end; ++j) {
      unsigned int u = y1[(size_t)csr2[j] * 64 + lane];
      sx += bflo(u);
      sy += bfhi(u);
    }
    ax = fmaf(di, sx, ax);
    ay = fmaf(di, sy, ay);
  }
  if (gcur == g0) {
    px = ax; py = ay;
  } else {
    atomicAdd(&Zb[(size_t)gcur * FDIM + 2 * lane], ax);
    atomicAdd(&Zb[(size_t)gcur * FDIM + 2 * lane + 1], ay);
  }
  ((float2*)Partials)[(size_t)wid * 64 + lane] = make_float2(px, py);
  if (lane == 0) Gid[wid] = g0;
}

// Reduce partials + Zb -> Z[g]; out[g] = Z@W2 + nodecount*b2.
__global__ __launch_bounds__(128) void k_poolzw2(
    const float* __restrict__ Partials, const int* __restrict__ Gid,
    const float* __restrict__ Zb, const int* __restrict__ gstart,
    const float* __restrict__ W2, const float* __restrict__ b2,
    float* __restrict__ out) {
  __shared__ float Zs[FDIM];
  int g = blockIdx.x, t = threadIdx.x;
  int s = gstart[g], e = gstart[g + 1];
  float acc = Zb[(size_t)g * FDIM + t];
  if (e > s) {
    int w0 = s / NPW, w1 = (e - 1) / NPW;
    for (int w = w0; w <= w1; ++w)
      if (Gid[w] == g) acc += Partials[(size_t)w * FDIM + t];
  }
  Zs[t] = acc;
  __syncthreads();
  float o = 0.f;
#pragma unroll 8
  for (int k = 0; k < FDIM; ++k) o = fmaf(Zs[k], W2[k * FDIM + t], o);
  out[(size_t)g * FDIM + t] = o + (float)(e - s) * b2[t];
}

extern "C" void kernel_launch(void* const* d_in, const int* in_sizes, int n_in,
                              void* d_out, int out_size, void* d_ws,
                              size_t ws_size, hipStream_t stream) {
  const int* x_type = (const int*)d_in[0];
  const int* edge_index = (const int*)d_in[1];
  const int* batch = (const int*)d_in[2];
  const float* emb = (const float*)d_in[3];
  const float* W1 = (const float*)d_in[4];
  const float* b1 = (const float*)d_in[5];
  const float* W2 = (const float*)d_in[6];
  const float* b2 = (const float*)d_in[7];
  float* out = (float*)d_out;

  const int* src = edge_index;
  const int* dst = edge_index + N_EDGES;

  char* p = (char*)d_ws;
  size_t off = 0;
  auto alloc = [&](size_t bytes) {
    void* r = p + off;
    off = (off + bytes + 255) & ~(size_t)255;
    return r;
  };
  float* dis = (float*)alloc(N_NODES * 4);
  int* cnt = (int*)alloc(N_NODES * 4);
  int* row_ptr = (int*)alloc((N_NODES + 1) * 4);
  int* blk = (int*)alloc(1024);
  int* gstart = (int*)alloc((N_GRAPHS + 1) * 4);
  unsigned int* nodeinfo = (unsigned int*)alloc(N_NODES * 4);
  unsigned int* Hist = (unsigned int*)alloc((size_t)NBLK * NQUAD * 4);
  unsigned int* Cur = (unsigned int*)alloc((size_t)NBLK * NQUAD * 4);
  unsigned char* rank8 = (unsigned char*)alloc(N_EDGES);
  unsigned int* csr1 = (unsigned int*)alloc((size_t)N_EDGES * 4);
  unsigned short* csr2 = (unsigned short*)alloc((size_t)N_EDGES * 2);
  unsigned short* T1 = (unsigned short*)alloc((size_t)NTYPES_PAD * FDIM * 2);
  unsigned int* y1 = (unsigned int*)alloc((size_t)N_NODES * 64 * 4);
  float* Partials = (float*)alloc((size_t)NW * FDIM * 4);
  int* Gid = (int*)alloc(NW * 4);
  float* Zb = (float*)alloc((size_t)N_GRAPHS * FDIM * 4);
  (void)ws_size;

  k_misc<<<256, 256, 0, stream>>>(Zb, batch, gstart);
  k_hist<<<NBLK, 512, 0, stream>>>(dst, Hist, rank8);
  k_colscan<<<(NQUAD + 255) / 256, 256, 0, stream>>>(Hist, x_type, Cur, cnt,
                                                     dis, nodeinfo);
  k_scan1<<<NB, 256, 0, stream>>>(cnt, row_ptr, blk);
  k_scan2<<<1, 256, 0, stream>>>(blk);
  k_scan3<<<NB, 256, 0, stream>>>(row_ptr, blk);
  k_fill2<<<(N_EDGES + 511) / 512, 512, 0, stream>>>(
      src, dst, row_ptr, Cur, rank8, nodeinfo, csr1, csr2);
  k_embw<<<(NTYPES_PAD + 63) / 64, 256, 0, stream>>>(emb, W1, T1);
  k_agg1<<<(N_NODES * 64 + 255) / 256, 256, 0, stream>>>(
      nodeinfo, T1, b1, row_ptr, csr1, dis, y1);
  k_aggpool<<<(NW * 64 + 255) / 256, 256, 0, stream>>>(
      y1, row_ptr, csr2, dis, batch, Partials, Gid, Zb);
  k_poolzw2<<<N_GRAPHS, 128, 0, stream>>>(Partials, Gid, Zb, gstart, W2, b2,
                                          out);
}

// Round 8
// 162.889 us; speedup vs baseline: 1.3044x; 1.0393x over previous
//
#include <hip/hip_runtime.h>

#define N_NODES 50000
#define N_EDGES 800000
#define N_GRAPHS 512
#define FDIM 128
#define NTYPES_PAD 1000

#define NBLK 128
#define CHUNK ((N_EDGES + NBLK - 1) / NBLK)  // 6250
#define NQUAD (N_NODES / 4)                  // 12500
#define NSB ((NQUAD + 255) / 256)            // 49 blocks in k_prep
#define NPW 4
#define NW ((N_NODES + NPW - 1) / NPW)       // 12500

typedef __bf16 bf16x8 __attribute__((ext_vector_type(8)));
typedef float f32x4 __attribute__((ext_vector_type(4)));
union BF8 { bf16x8 v; unsigned short u[8]; };

__device__ __forceinline__ unsigned short f2bf(float f) {
  unsigned int u = __float_as_uint(f);
  unsigned int r = (u + 0x7FFFu + ((u >> 16) & 1u)) >> 16;
  return (unsigned short)r;
}
__device__ __forceinline__ float bflo(unsigned int v) {
  return __uint_as_float(v << 16);
}
__device__ __forceinline__ float bfhi(unsigned int v) {
  return __uint_as_float(v & 0xFFFF0000u);
}

// Per-chunk LDS histogram (8-bit packed); emits per-edge local rank.
// Also resets k_prep's done-counter for this launch (graph replays).
__global__ __launch_bounds__(512) void k_hist(const int* __restrict__ dst,
                                              unsigned int* __restrict__ Hist,
                                              unsigned char* __restrict__ rank8,
                                              int* __restrict__ g_done) {
  __shared__ unsigned int h[NQUAD];  // 50 KB
  int b = blockIdx.x, t = threadIdx.x;
  if (b == 0 && t == 0) *g_done = 0;
  for (int i = t; i < NQUAD; i += 512) h[i] = 0;
  __syncthreads();
  int e0 = b * CHUNK, e1 = min(e0 + CHUNK, N_EDGES);
  for (int e = e0 + t; e < e1; e += 512) {
    int d = dst[e];
    unsigned int sh = (d & 3) * 8;
    unsigned int old = atomicAdd(&h[d >> 2], 1u << sh);
    rank8[e] = (unsigned char)((old >> sh) & 0xFFu);
  }
  __syncthreads();
  unsigned int* H = Hist + (size_t)b * NQUAD;
  for (int i = t; i < NQUAD; i += 512) H[i] = h[i];
}

// Fused: per-node cross-chunk prefix (Cur bases) + cnt/dis/nodeinfo +
// global row_ptr scan (device-scope all-posted barrier over NSB blocks) +
// Zb zero + gstart. One launch replaces colscan/scan1/scan2/scan3/misc.
__global__ __launch_bounds__(256) void k_prep(
    const unsigned int* __restrict__ Hist, const int* __restrict__ x_type,
    const int* __restrict__ batch, unsigned int* __restrict__ Cur,
    float* __restrict__ dis, unsigned int* __restrict__ nodeinfo,
    int* __restrict__ row_ptr, float* __restrict__ Zb,
    int* __restrict__ gstart, int* __restrict__ g_bsum,
    int* __restrict__ g_done) {
  int blk = blockIdx.x, tid = threadIdx.x;
  int q = blk * 256 + tid;
  int gt = blk * 256 + tid;

  // Zb zero (independent streaming work)
  for (int i = gt; i < N_GRAPHS * FDIM; i += NSB * 256) Zb[i] = 0.0f;

  // gstart from sorted batch: this thread covers nodes [4q, 4q+4)
  if (q < NQUAD) {
    int i0 = 4 * q;
    int prev = (i0 == 0) ? -1 : batch[i0 - 1];
#pragma unroll
    for (int k = 0; k < 4; ++k) {
      int i = i0 + k;
      int bb = batch[i];
      for (int g = prev + 1; g <= bb; ++g) gstart[g] = i;
      prev = bb;
    }
    if (i0 + 3 == N_NODES - 1)
      for (int g = prev + 1; g <= N_GRAPHS; ++g) gstart[g] = N_NODES;
  }

  // per-node prefix over the 128 chunk histograms
  unsigned int r0 = 0, r1 = 0, r2 = 0, r3 = 0;
  if (q < NQUAD) {
    for (int b = 0; b < NBLK; ++b) {
      unsigned int v = Hist[(size_t)b * NQUAD + q];
      Cur[(size_t)b * NQUAD + q] =
          (r0 & 255u) | ((r1 & 255u) << 8) | ((r2 & 255u) << 16) | (r3 << 24);
      r0 += v & 255u;
      r1 += (v >> 8) & 255u;
      r2 += (v >> 16) & 255u;
      r3 += v >> 24;
    }
    float4 dv = make_float4(rsqrtf((float)r0 + 1.f), rsqrtf((float)r1 + 1.f),
                            rsqrtf((float)r2 + 1.f), rsqrtf((float)r3 + 1.f));
    ((float4*)dis)[q] = dv;
    int4 xt = ((const int4*)x_type)[q];
    ((uint4*)nodeinfo)[q] = make_uint4(
        (unsigned int)xt.x | (r0 << 16), (unsigned int)xt.y | (r1 << 16),
        (unsigned int)xt.z | (r2 << 16), (unsigned int)xt.w | (r3 << 16));
  }

  // block-level exclusive scan of per-thread sums
  int tsum = (q < NQUAD) ? (int)(r0 + r1 + r2 + r3) : 0;
  __shared__ int s[256];
  s[tid] = tsum;
  __syncthreads();
  for (int d = 1; d < 256; d <<= 1) {
    int u = (tid >= d) ? s[tid - d] : 0;
    __syncthreads();
    s[tid] += u;
    __syncthreads();
  }
  int excl = s[tid] - tsum;
  int btotal = s[255];

  // post + all-posted barrier (device-scope atomics; 49 blocks co-resident)
  if (tid == 0) {
    atomicExch(&g_bsum[blk], btotal);
    __threadfence();
    atomicAdd(g_done, 1);
    while (atomicAdd(g_done, 0) < NSB) {
    }
  }
  __syncthreads();
  __shared__ int sb[NSB];
  if (tid < NSB) sb[tid] = atomicAdd(&g_bsum[tid], 0);
  __syncthreads();
  int bpref = 0;
  for (int t = 0; t < blk; ++t) bpref += sb[t];

  if (q < NQUAD) {
    int base = bpref + excl;
    ((int4*)row_ptr)[q] =
        make_int4(base, base + (int)r0, base + (int)(r0 + r1),
                  base + (int)(r0 + r1 + r2));
  }
  if (q == NQUAD - 1) row_ptr[N_NODES] = N_EDGES;
}

// CSR fill, no atomics. csr1 = nodeinfo[s]; csr2 = (u16)s.
__global__ __launch_bounds__(512) void k_fill2(
    const int* __restrict__ src, const int* __restrict__ dst,
    const int* __restrict__ row_ptr, const unsigned int* __restrict__ Cur,
    const unsigned char* __restrict__ rank8,
    const unsigned int* __restrict__ nodeinfo, unsigned int* __restrict__ csr1,
    unsigned short* __restrict__ csr2) {
  int e = blockIdx.x * blockDim.x + threadIdx.x;
  if (e >= N_EDGES) return;
  int b = e / CHUNK;
  int s = src[e], d = dst[e];
  unsigned int cw = Cur[(size_t)b * NQUAD + (d >> 2)];
  int base = (int)((cw >> ((d & 3) * 8)) & 0xFFu);
  int pos = row_ptr[d] + base + (int)rank8[e];
  csr1[pos] = nodeinfo[s];
  csr2[pos] = (unsigned short)s;
}

// T1 = emb @ W1 [1000x128] bf16; converts W1 f32->swizzled bf16 LDS in-block.
__global__ __launch_bounds__(256) void k_embw(
    const float* __restrict__ emb, const float* __restrict__ W1,
    unsigned short* __restrict__ T1) {
  __shared__ unsigned short Ws[128 * 128];
  int t = threadIdx.x, w = t >> 6, l = t & 63;
  for (int i = t; i < 16384; i += 256) {
    int k = i >> 7, n = i & 127;
    Ws[n * 128 + (k ^ ((n & 15) << 3))] = f2bf(W1[i]);
  }
  int row0 = blockIdx.x * 64 + w * 16;
  int arow = row0 + (l & 15);
  bool ok = arow < NTYPES_PAD;
  bf16x8 a[4];
#pragma unroll
  for (int ks = 0; ks < 4; ++ks) {
    BF8 av;
    const float* ap = emb + (size_t)arow * FDIM + (l >> 4) * 8 + ks * 32;
#pragma unroll
    for (int i = 0; i < 8; ++i) av.u[i] = ok ? f2bf(ap[i]) : 0;
    a[ks] = av.v;
  }
  __syncthreads();
  f32x4 acc[8] = {};
#pragma unroll
  for (int ks = 0; ks < 4; ++ks) {
#pragma unroll
    for (int ct = 0; ct < 8; ++ct) {
      int n = ct * 16 + (l & 15);
      int kk = (ks * 32 + (l >> 4) * 8) ^ ((n & 15) << 3);
      bf16x8 b = *(const bf16x8*)&Ws[n * 128 + kk];
      acc[ct] =
          __builtin_amdgcn_mfma_f32_16x16x32_bf16(a[ks], b, acc[ct], 0, 0, 0);
    }
  }
#pragma unroll
  for (int ct = 0; ct < 8; ++ct) {
    int col = ct * 16 + (l & 15);
#pragma unroll
    for (int r = 0; r < 4; ++r) {
      int row = row0 + (l >> 4) * 4 + r;
      if (row < NTYPES_PAD) T1[row * FDIM + col] = f2bf(acc[ct][r]);
    }
  }
}

// Layer 1: ytilde = di * relu(di*(di*T1[type_d] + sum rsqrt(cnt_s+1)*
// T1[type_s]) + b1). 1 wave/node, unroll 8.
__global__ void k_agg1(const unsigned int* __restrict__ nodeinfo,
                       const unsigned short* __restrict__ T1,
                       const float* __restrict__ b1,
                       const int* __restrict__ row_ptr,
                       const unsigned int* __restrict__ csr1,
                       const float* __restrict__ dis,
                       unsigned int* __restrict__ y1) {
  int gid = blockIdx.x * blockDim.x + threadIdx.x;
  int node = gid >> 6;
  int lane = gid & 63;
  if (node >= N_NODES) return;
  const unsigned int* T = (const unsigned int*)T1;
  float di = dis[node];
  unsigned int ni = nodeinfo[node];
  unsigned int v = T[(size_t)(ni & 0xFFFFu) * 64 + lane];
  float ax = bflo(v) * di, ay = bfhi(v) * di;
  int j = row_ptr[node], end = row_ptr[node + 1];
  for (; j + 8 <= end; j += 8) {
    unsigned int e0 = csr1[j], e1 = csr1[j + 1];
    unsigned int e2 = csr1[j + 2], e3 = csr1[j + 3];
    unsigned int e4 = csr1[j + 4], e5 = csr1[j + 5];
    unsigned int e6 = csr1[j + 6], e7 = csr1[j + 7];
    unsigned int u0 = T[(size_t)(e0 & 0xFFFFu) * 64 + lane];
    unsigned int u1 = T[(size_t)(e1 & 0xFFFFu) * 64 + lane];
    unsigned int u2 = T[(size_t)(e2 & 0xFFFFu) * 64 + lane];
    unsigned int u3 = T[(size_t)(e3 & 0xFFFFu) * 64 + lane];
    unsigned int u4 = T[(size_t)(e4 & 0xFFFFu) * 64 + lane];
    unsigned int u5 = T[(size_t)(e5 & 0xFFFFu) * 64 + lane];
    unsigned int u6 = T[(size_t)(e6 & 0xFFFFu) * 64 + lane];
    unsigned int u7 = T[(size_t)(e7 & 0xFFFFu) * 64 + lane];
    float n0 = rsqrtf((float)(e0 >> 16) + 1.f);
    float n1 = rsqrtf((float)(e1 >> 16) + 1.f);
    float n2 = rsqrtf((float)(e2 >> 16) + 1.f);
    float n3 = rsqrtf((float)(e3 >> 16) + 1.f);
    float n4 = rsqrtf((float)(e4 >> 16) + 1.f);
    float n5 = rsqrtf((float)(e5 >> 16) + 1.f);
    float n6 = rsqrtf((float)(e6 >> 16) + 1.f);
    float n7 = rsqrtf((float)(e7 >> 16) + 1.f);
    ax = fmaf(bflo(u0), n0, ax); ay = fmaf(bfhi(u0), n0, ay);
    ax = fmaf(bflo(u1), n1, ax); ay = fmaf(bfhi(u1), n1, ay);
    ax = fmaf(bflo(u2), n2, ax); ay = fmaf(bfhi(u2), n2, ay);
    ax = fmaf(bflo(u3), n3, ax); ay = fmaf(bfhi(u3), n3, ay);
    ax = fmaf(bflo(u4), n4, ax); ay = fmaf(bfhi(u4), n4, ay);
    ax = fmaf(bflo(u5), n5, ax); ay = fmaf(bfhi(u5), n5, ay);
    ax = fmaf(bflo(u6), n6, ax); ay = fmaf(bfhi(u6), n6, ay);
    ax = fmaf(bflo(u7), n7, ax); ay = fmaf(bfhi(u7), n7, ay);
  }
  for (; j < end; ++j) {
    unsigned int e = csr1[j];
    unsigned int u = T[(size_t)(e & 0xFFFFu) * 64 + lane];
    float nw = rsqrtf((float)(e >> 16) + 1.f);
    ax = fmaf(bflo(u), nw, ax);
    ay = fmaf(bfhi(u), nw, ay);
  }
  float2 bb = ((const float2*)b1)[lane];
  ax = fmaxf(fmaf(di, ax, bb.x), 0.f) * di;
  ay = fmaxf(fmaf(di, ay, bb.y), 0.f) * di;
  y1[(size_t)node * 64 + lane] = (unsigned int)f2bf(ax) |
                                 ((unsigned int)f2bf(ay) << 16);
}

// Pooled layer 2 over pre-scaled ytilde; unroll 8; one wave per NPW nodes.
__global__ void k_aggpool(const unsigned int* __restrict__ y1,
                          const int* __restrict__ row_ptr,
                          const unsigned short* __restrict__ csr2,
                          const float* __restrict__ dis,
                          const int* __restrict__ batch,
                          float* __restrict__ Partials, int* __restrict__ Gid,
                          float* __restrict__ Zb) {
  int gid = blockIdx.x * blockDim.x + threadIdx.x;
  int wid = gid >> 6;
  int lane = gid & 63;
  int n0 = wid * NPW;
  if (n0 >= N_NODES) return;
  int nend = min(n0 + NPW, N_NODES);
  int g0 = batch[n0];
  int gcur = g0;
  float px = 0.f, py = 0.f;
  float ax = 0.f, ay = 0.f;
  for (int node = n0; node < nend; ++node) {
    int g = batch[node];
    if (g != gcur) {
      if (gcur == g0) {
        px = ax; py = ay;
      } else {
        atomicAdd(&Zb[(size_t)gcur * FDIM + 2 * lane], ax);
        atomicAdd(&Zb[(size_t)gcur * FDIM + 2 * lane + 1], ay);
      }
      ax = 0.f; ay = 0.f;
      gcur = g;
    }
    float di = dis[node];
    unsigned int v = y1[(size_t)node * 64 + lane];
    float sx = bflo(v), sy = bfhi(v);
    int j = row_ptr[node], end = row_ptr[node + 1];
    for (; j + 8 <= end; j += 8) {
      int s0 = csr2[j], s1 = csr2[j + 1], s2 = csr2[j + 2], s3 = csr2[j + 3];
      int s4 = csr2[j + 4], s5 = csr2[j + 5], s6 = csr2[j + 6], s7 = csr2[j + 7];
      unsigned int u0 = y1[(size_t)s0 * 64 + lane];
      unsigned int u1 = y1[(size_t)s1 * 64 + lane];
      unsigned int u2 = y1[(size_t)s2 * 64 + lane];
      unsigned int u3 = y1[(size_t)s3 * 64 + lane];
      unsigned int u4 = y1[(size_t)s4 * 64 + lane];
      unsigned int u5 = y1[(size_t)s5 * 64 + lane];
      unsigned int u6 = y1[(size_t)s6 * 64 + lane];
      unsigned int u7 = y1[(size_t)s7 * 64 + lane];
      sx += bflo(u0) + bflo(u1) + bflo(u2) + bflo(u3);
      sy += bfhi(u0) + bfhi(u1) + bfhi(u2) + bfhi(u3);
      sx += bflo(u4) + bflo(u5) + bflo(u6) + bflo(u7);
      sy += bfhi(u4) + bfhi(u5) + bfhi(u6) + bfhi(u7);
    }
    for (; j < end; ++j) {
      unsigned int u = y1[(size_t)csr2[j] * 64 + lane];
      sx += bflo(u);
      sy += bfhi(u);
    }
    ax = fmaf(di, sx, ax);
    ay = fmaf(di, sy, ay);
  }
  if (gcur == g0) {
    px = ax; py = ay;
  } else {
    atomicAdd(&Zb[(size_t)gcur * FDIM + 2 * lane], ax);
    atomicAdd(&Zb[(size_t)gcur * FDIM + 2 * lane + 1], ay);
  }
  ((float2*)Partials)[(size_t)wid * 64 + lane] = make_float2(px, py);
  if (lane == 0) Gid[wid] = g0;
}

// Reduce partials + Zb -> Z[g]; out[g] = Z@W2 + nodecount*b2.
__global__ __launch_bounds__(128) void k_poolzw2(
    const float* __restrict__ Partials, const int* __restrict__ Gid,
    const float* __restrict__ Zb, const int* __restrict__ gstart,
    const float* __restrict__ W2, const float* __restrict__ b2,
    float* __restrict__ out) {
  __shared__ float Zs[FDIM];
  int g = blockIdx.x, t = threadIdx.x;
  int s = gstart[g], e = gstart[g + 1];
  float acc = Zb[(size_t)g * FDIM + t];
  if (e > s) {
    int w0 = s / NPW, w1 = (e - 1) / NPW;
    for (int w = w0; w <= w1; ++w)
      if (Gid[w] == g) acc += Partials[(size_t)w * FDIM + t];
  }
  Zs[t] = acc;
  __syncthreads();
  float o = 0.f;
#pragma unroll 8
  for (int k = 0; k < FDIM; ++k) o = fmaf(Zs[k], W2[k * FDIM + t], o);
  out[(size_t)g * FDIM + t] = o + (float)(e - s) * b2[t];
}

extern "C" void kernel_launch(void* const* d_in, const int* in_sizes, int n_in,
                              void* d_out, int out_size, void* d_ws,
                              size_t ws_size, hipStream_t stream) {
  const int* x_type = (const int*)d_in[0];
  const int* edge_index = (const int*)d_in[1];
  const int* batch = (const int*)d_in[2];
  const float* emb = (const float*)d_in[3];
  const float* W1 = (const float*)d_in[4];
  const float* b1 = (const float*)d_in[5];
  const float* W2 = (const float*)d_in[6];
  const float* b2 = (const float*)d_in[7];
  float* out = (float*)d_out;

  const int* src = edge_index;
  const int* dst = edge_index + N_EDGES;

  char* p = (char*)d_ws;
  size_t off = 0;
  auto alloc = [&](size_t bytes) {
    void* r = p + off;
    off = (off + bytes + 255) & ~(size_t)255;
    return r;
  };
  float* dis = (float*)alloc(N_NODES * 4);
  int* row_ptr = (int*)alloc((N_NODES + 1) * 4);
  int* gstart = (int*)alloc((N_GRAPHS + 1) * 4);
  unsigned int* nodeinfo = (unsigned int*)alloc(N_NODES * 4);
  unsigned int* Hist = (unsigned int*)alloc((size_t)NBLK * NQUAD * 4);
  unsigned int* Cur = (unsigned int*)alloc((size_t)NBLK * NQUAD * 4);
  unsigned char* rank8 = (unsigned char*)alloc(N_EDGES);
  unsigned int* csr1 = (unsigned int*)alloc((size_t)N_EDGES * 4);
  unsigned short* csr2 = (unsigned short*)alloc((size_t)N_EDGES * 2);
  unsigned short* T1 = (unsigned short*)alloc((size_t)NTYPES_PAD * FDIM * 2);
  unsigned int* y1 = (unsigned int*)alloc((size_t)N_NODES * 64 * 4);
  float* Partials = (float*)alloc((size_t)NW * FDIM * 4);
  int* Gid = (int*)alloc(NW * 4);
  float* Zb = (float*)alloc((size_t)N_GRAPHS * FDIM * 4);
  int* g_bsum = (int*)alloc(NSB * 4);
  int* g_done = (int*)alloc(4);
  (void)ws_size;

  k_hist<<<NBLK, 512, 0, stream>>>(dst, Hist, rank8, g_done);
  k_prep<<<NSB, 256, 0, stream>>>(Hist, x_type, batch, Cur, dis, nodeinfo,
                                  row_ptr, Zb, gstart, g_bsum, g_done);
  k_fill2<<<(N_EDGES + 511) / 512, 512, 0, stream>>>(
      src, dst, row_ptr, Cur, rank8, nodeinfo, csr1, csr2);
  k_embw<<<(NTYPES_PAD + 63) / 64, 256, 0, stream>>>(emb, W1, T1);
  k_agg1<<<(N_NODES * 64 + 255) / 256, 256, 0, stream>>>(
      nodeinfo, T1, b1, row_ptr, csr1, dis, y1);
  k_aggpool<<<(NW * 64 + 255) / 256, 256, 0, stream>>>(
      y1, row_ptr, csr2, dis, batch, Partials, Gid, Zb);
  k_poolzw2<<<N_GRAPHS, 128, 0, stream>>>(Partials, Gid, Zb, gstart, W2, b2,
                                          out);
}

// Round 9
// 151.305 us; speedup vs baseline: 1.4043x; 1.0766x over previous
//
#include <hip/hip_runtime.h>

#define N_NODES 50000
#define N_EDGES 800000
#define N_GRAPHS 512
#define FDIM 128
#define NTYPES_PAD 1000

#define NBLK 128
#define CHUNK ((N_EDGES + NBLK - 1) / NBLK)  // 6250
#define NQUAD (N_NODES / 4)                  // 12500
#define NSB ((NQUAD + 127) / 128)            // 98 blocks in k_prep
#define NPW 4
#define NW ((N_NODES + NPW - 1) / NPW)       // 12500

typedef __bf16 bf16x8 __attribute__((ext_vector_type(8)));
typedef float f32x4 __attribute__((ext_vector_type(4)));
union BF8 { bf16x8 v; unsigned short u[8]; };

__device__ __forceinline__ unsigned short f2bf(float f) {
  unsigned int u = __float_as_uint(f);
  unsigned int r = (u + 0x7FFFu + ((u >> 16) & 1u)) >> 16;
  return (unsigned short)r;
}
__device__ __forceinline__ float bflo(unsigned int v) {
  return __uint_as_float(v << 16);
}
__device__ __forceinline__ float bfhi(unsigned int v) {
  return __uint_as_float(v & 0xFFFF0000u);
}

// Per-chunk LDS histogram (8-bit packed); emits per-edge local rank.
// Also resets k_prep's done-counter for this launch (graph replays).
__global__ __launch_bounds__(512) void k_hist(const int* __restrict__ dst,
                                              unsigned int* __restrict__ Hist,
                                              unsigned char* __restrict__ rank8,
                                              int* __restrict__ g_done) {
  __shared__ unsigned int h[NQUAD];  // 50 KB
  int b = blockIdx.x, t = threadIdx.x;
  if (b == 0 && t == 0) *g_done = 0;
  for (int i = t; i < NQUAD; i += 512) h[i] = 0;
  __syncthreads();
  int e0 = b * CHUNK, e1 = min(e0 + CHUNK, N_EDGES);
  for (int e = e0 + t; e < e1; e += 512) {
    int d = dst[e];
    unsigned int sh = (d & 3) * 8;
    unsigned int old = atomicAdd(&h[d >> 2], 1u << sh);
    rank8[e] = (unsigned char)((old >> sh) & 0xFFu);
  }
  __syncthreads();
  unsigned int* H = Hist + (size_t)b * NQUAD;
  for (int i = t; i < NQUAD; i += 512) H[i] = h[i];
}

// Fused: per-node cross-chunk prefix (Cur bases) + dis + global row_ptr scan
// (device-scope all-posted barrier over NSB blocks) + Zb zero + gstart.
__global__ __launch_bounds__(128) void k_prep(
    const unsigned int* __restrict__ Hist, const int* __restrict__ batch,
    unsigned int* __restrict__ Cur, float* __restrict__ dis,
    int* __restrict__ row_ptr, float* __restrict__ Zb,
    int* __restrict__ gstart, int* __restrict__ g_bsum,
    int* __restrict__ g_done) {
  int blk = blockIdx.x, tid = threadIdx.x;
  int q = blk * 128 + tid;

  // Zb zero (independent streaming work)
  for (int i = blk * 128 + tid; i < N_GRAPHS * FDIM; i += NSB * 128)
    Zb[i] = 0.0f;

  // gstart from sorted batch: this thread covers nodes [4q, 4q+4)
  if (q < NQUAD) {
    int i0 = 4 * q;
    int prev = (i0 == 0) ? -1 : batch[i0 - 1];
#pragma unroll
    for (int k = 0; k < 4; ++k) {
      int i = i0 + k;
      int bb = batch[i];
      for (int g = prev + 1; g <= bb; ++g) gstart[g] = i;
      prev = bb;
    }
    if (i0 + 3 == N_NODES - 1)
      for (int g = prev + 1; g <= N_GRAPHS; ++g) gstart[g] = N_NODES;
  }

  // per-node prefix over the 128 chunk histograms
  unsigned int r0 = 0, r1 = 0, r2 = 0, r3 = 0;
  if (q < NQUAD) {
    for (int b = 0; b < NBLK; ++b) {
      unsigned int v = Hist[(size_t)b * NQUAD + q];
      Cur[(size_t)b * NQUAD + q] =
          (r0 & 255u) | ((r1 & 255u) << 8) | ((r2 & 255u) << 16) | (r3 << 24);
      r0 += v & 255u;
      r1 += (v >> 8) & 255u;
      r2 += (v >> 16) & 255u;
      r3 += v >> 24;
    }
    float4 dv = make_float4(rsqrtf((float)r0 + 1.f), rsqrtf((float)r1 + 1.f),
                            rsqrtf((float)r2 + 1.f), rsqrtf((float)r3 + 1.f));
    ((float4*)dis)[q] = dv;
  }

  // block-level exclusive scan of per-thread sums
  int tsum = (q < NQUAD) ? (int)(r0 + r1 + r2 + r3) : 0;
  __shared__ int s[128];
  s[tid] = tsum;
  __syncthreads();
  for (int d = 1; d < 128; d <<= 1) {
    int u = (tid >= d) ? s[tid - d] : 0;
    __syncthreads();
    s[tid] += u;
    __syncthreads();
  }
  int excl = s[tid] - tsum;
  int btotal = s[127];

  // post + all-posted barrier (device-scope atomics; NSB blocks co-resident)
  if (tid == 0) {
    atomicExch(&g_bsum[blk], btotal);
    __threadfence();
    atomicAdd(g_done, 1);
    while (atomicAdd(g_done, 0) < NSB) {
    }
  }
  __syncthreads();
  __shared__ int sb[NSB];
  if (tid < NSB) sb[tid] = atomicAdd(&g_bsum[tid], 0);
  __syncthreads();
  int bpref = 0;
  for (int t = 0; t < blk; ++t) bpref += sb[t];

  if (q < NQUAD) {
    int base = bpref + excl;
    ((int4*)row_ptr)[q] =
        make_int4(base, base + (int)r0, base + (int)(r0 + r1),
                  base + (int)(r0 + r1 + r2));
  }
  if (q == NQUAD - 1) row_ptr[N_NODES] = N_EDGES;
}

// CSR fill, no atomics. One 8B entry: src | type<<16 | bf16(dis_dst)<<32.
__global__ __launch_bounds__(512) void k_fill2(
    const int* __restrict__ src, const int* __restrict__ dst,
    const int* __restrict__ x_type, const int* __restrict__ row_ptr,
    const unsigned int* __restrict__ Cur, const unsigned char* __restrict__ rank8,
    const float* __restrict__ dis, unsigned long long* __restrict__ csr) {
  int e = blockIdx.x * blockDim.x + threadIdx.x;
  if (e >= N_EDGES) return;
  int b = e / CHUNK;
  int s = src[e], d = dst[e];
  unsigned int cw = Cur[(size_t)b * NQUAD + (d >> 2)];
  int base = (int)((cw >> ((d & 3) * 8)) & 0xFFu);
  int pos = row_ptr[d] + base + (int)rank8[e];
  unsigned int lo = (unsigned int)s | ((unsigned int)x_type[s] << 16);
  unsigned int hi = (unsigned int)f2bf(dis[d]);
  csr[pos] = (unsigned long long)lo | ((unsigned long long)hi << 32);
}

// T1 = emb @ W1 [1000x128] bf16; converts W1 f32->swizzled bf16 LDS in-block.
__global__ __launch_bounds__(256) void k_embw(
    const float* __restrict__ emb, const float* __restrict__ W1,
    unsigned short* __restrict__ T1) {
  __shared__ unsigned short Ws[128 * 128];
  int t = threadIdx.x, w = t >> 6, l = t & 63;
  for (int i = t; i < 16384; i += 256) {
    int k = i >> 7, n = i & 127;
    Ws[n * 128 + (k ^ ((n & 15) << 3))] = f2bf(W1[i]);
  }
  int row0 = blockIdx.x * 64 + w * 16;
  int arow = row0 + (l & 15);
  bool ok = arow < NTYPES_PAD;
  bf16x8 a[4];
#pragma unroll
  for (int ks = 0; ks < 4; ++ks) {
    BF8 av;
    const float* ap = emb + (size_t)arow * FDIM + (l >> 4) * 8 + ks * 32;
#pragma unroll
    for (int i = 0; i < 8; ++i) av.u[i] = ok ? f2bf(ap[i]) : 0;
    a[ks] = av.v;
  }
  __syncthreads();
  f32x4 acc[8] = {};
#pragma unroll
  for (int ks = 0; ks < 4; ++ks) {
#pragma unroll
    for (int ct = 0; ct < 8; ++ct) {
      int n = ct * 16 + (l & 15);
      int kk = (ks * 32 + (l >> 4) * 8) ^ ((n & 15) << 3);
      bf16x8 b = *(const bf16x8*)&Ws[n * 128 + kk];
      acc[ct] =
          __builtin_amdgcn_mfma_f32_16x16x32_bf16(a[ks], b, acc[ct], 0, 0, 0);
    }
  }
#pragma unroll
  for (int ct = 0; ct < 8; ++ct) {
    int col = ct * 16 + (l & 15);
#pragma unroll
    for (int r = 0; r < 4; ++r) {
      int row = row0 + (l >> 4) * 4 + r;
      if (row < NTYPES_PAD) T1[row * FDIM + col] = f2bf(acc[ct][r]);
    }
  }
}

// Layer 1: ytilde = di * relu(di*(di*T1[type_d] + sum dis_s*T1[type_s]) + b1).
// 1 wave/node; unroll 8/4/1 ladder; dis_s from L2-resident table.
__global__ void k_agg1(const int* __restrict__ x_type,
                       const unsigned short* __restrict__ T1,
                       const float* __restrict__ b1,
                       const int* __restrict__ row_ptr,
                       const unsigned long long* __restrict__ csr,
                       const float* __restrict__ dis,
                       unsigned int* __restrict__ y1) {
  int gid = blockIdx.x * blockDim.x + threadIdx.x;
  int node = gid >> 6;
  int lane = gid & 63;
  if (node >= N_NODES) return;
  const unsigned int* T = (const unsigned int*)T1;
  const unsigned int* C = (const unsigned int*)csr;  // lo words at even idx
  float di = dis[node];
  unsigned int v = T[(size_t)x_type[node] * 64 + lane];
  float ax = bflo(v) * di, ay = bfhi(v) * di;
  int j = row_ptr[node], end = row_ptr[node + 1];
  for (; j + 8 <= end; j += 8) {
    unsigned int e0 = C[2 * j], e1 = C[2 * j + 2];
    unsigned int e2 = C[2 * j + 4], e3 = C[2 * j + 6];
    unsigned int e4 = C[2 * j + 8], e5 = C[2 * j + 10];
    unsigned int e6 = C[2 * j + 12], e7 = C[2 * j + 14];
    unsigned int u0 = T[(size_t)(e0 >> 16) * 64 + lane];
    unsigned int u1 = T[(size_t)(e1 >> 16) * 64 + lane];
    unsigned int u2 = T[(size_t)(e2 >> 16) * 64 + lane];
    unsigned int u3 = T[(size_t)(e3 >> 16) * 64 + lane];
    unsigned int u4 = T[(size_t)(e4 >> 16) * 64 + lane];
    unsigned int u5 = T[(size_t)(e5 >> 16) * 64 + lane];
    unsigned int u6 = T[(size_t)(e6 >> 16) * 64 + lane];
    unsigned int u7 = T[(size_t)(e7 >> 16) * 64 + lane];
    float n0 = dis[e0 & 0xFFFFu], n1 = dis[e1 & 0xFFFFu];
    float n2 = dis[e2 & 0xFFFFu], n3 = dis[e3 & 0xFFFFu];
    float n4 = dis[e4 & 0xFFFFu], n5 = dis[e5 & 0xFFFFu];
    float n6 = dis[e6 & 0xFFFFu], n7 = dis[e7 & 0xFFFFu];
    ax = fmaf(bflo(u0), n0, ax); ay = fmaf(bfhi(u0), n0, ay);
    ax = fmaf(bflo(u1), n1, ax); ay = fmaf(bfhi(u1), n1, ay);
    ax = fmaf(bflo(u2), n2, ax); ay = fmaf(bfhi(u2), n2, ay);
    ax = fmaf(bflo(u3), n3, ax); ay = fmaf(bfhi(u3), n3, ay);
    ax = fmaf(bflo(u4), n4, ax); ay = fmaf(bfhi(u4), n4, ay);
    ax = fmaf(bflo(u5), n5, ax); ay = fmaf(bfhi(u5), n5, ay);
    ax = fmaf(bflo(u6), n6, ax); ay = fmaf(bfhi(u6), n6, ay);
    ax = fmaf(bflo(u7), n7, ax); ay = fmaf(bfhi(u7), n7, ay);
  }
  for (; j + 4 <= end; j += 4) {
    unsigned int e0 = C[2 * j], e1 = C[2 * j + 2];
    unsigned int e2 = C[2 * j + 4], e3 = C[2 * j + 6];
    unsigned int u0 = T[(size_t)(e0 >> 16) * 64 + lane];
    unsigned int u1 = T[(size_t)(e1 >> 16) * 64 + lane];
    unsigned int u2 = T[(size_t)(e2 >> 16) * 64 + lane];
    unsigned int u3 = T[(size_t)(e3 >> 16) * 64 + lane];
    float n0 = dis[e0 & 0xFFFFu], n1 = dis[e1 & 0xFFFFu];
    float n2 = dis[e2 & 0xFFFFu], n3 = dis[e3 & 0xFFFFu];
    ax = fmaf(bflo(u0), n0, ax); ay = fmaf(bfhi(u0), n0, ay);
    ax = fmaf(bflo(u1), n1, ax); ay = fmaf(bfhi(u1), n1, ay);
    ax = fmaf(bflo(u2), n2, ax); ay = fmaf(bfhi(u2), n2, ay);
    ax = fmaf(bflo(u3), n3, ax); ay = fmaf(bfhi(u3), n3, ay);
  }
  for (; j < end; ++j) {
    unsigned int e = C[2 * j];
    unsigned int u = T[(size_t)(e >> 16) * 64 + lane];
    float nw = dis[e & 0xFFFFu];
    ax = fmaf(bflo(u), nw, ax);
    ay = fmaf(bfhi(u), nw, ay);
  }
  float2 bb = ((const float2*)b1)[lane];
  ax = fmaxf(fmaf(di, ax, bb.x), 0.f) * di;
  ay = fmaxf(fmaf(di, ay, bb.y), 0.f) * di;
  y1[(size_t)node * 64 + lane] = (unsigned int)f2bf(ax) |
                                 ((unsigned int)f2bf(ay) << 16);
}

// Pooled layer 2: per graph-run of the wave's NPW consecutive nodes, the csr
// range is CONTIGUOUS -> flat branch-free gather loop (w = bf16 dis_dst is in
// the csr entry), unroll 16/4/1. Self terms per node. First run -> Partials;
// later runs (rare) -> Zb atomics.
__global__ void k_aggpool(const unsigned int* __restrict__ y1,
                          const int* __restrict__ row_ptr,
                          const unsigned long long* __restrict__ csr,
                          const float* __restrict__ dis,
                          const int* __restrict__ batch,
                          float* __restrict__ Partials, int* __restrict__ Gid,
                          float* __restrict__ Zb) {
  int gid = blockIdx.x * blockDim.x + threadIdx.x;
  int wid = gid >> 6;
  int lane = gid & 63;
  int n0 = wid * NPW;
  if (n0 >= N_NODES) return;
  int nend = min(n0 + NPW, N_NODES);
  int g0 = batch[n0];
  float px = 0.f, py = 0.f;
  int node = n0;
  while (node < nend) {
    int g = batch[node];
    int rend = node + 1;
    while (rend < nend && batch[rend] == g) ++rend;  // run [node, rend)
    float sx = 0.f, sy = 0.f;
    for (int n = node; n < rend; ++n) {  // self-loop terms
      float dn = dis[n];
      unsigned int v = y1[(size_t)n * 64 + lane];
      sx = fmaf(dn, bflo(v), sx);
      sy = fmaf(dn, bfhi(v), sy);
    }
    int j = row_ptr[node], jend = row_ptr[rend];
    for (; j + 16 <= jend; j += 16) {
#pragma unroll
      for (int k = 0; k < 16; ++k) {
        unsigned long long e = csr[j + k];
        unsigned int u = y1[(size_t)(e & 0xFFFFu) * 64 + lane];
        float w = __uint_as_float(((unsigned int)(e >> 32)) << 16);
        sx = fmaf(bflo(u), w, sx);
        sy = fmaf(bfhi(u), w, sy);
      }
    }
    for (; j + 4 <= jend; j += 4) {
#pragma unroll
      for (int k = 0; k < 4; ++k) {
        unsigned long long e = csr[j + k];
        unsigned int u = y1[(size_t)(e & 0xFFFFu) * 64 + lane];
        float w = __uint_as_float(((unsigned int)(e >> 32)) << 16);
        sx = fmaf(bflo(u), w, sx);
        sy = fmaf(bfhi(u), w, sy);
      }
    }
    for (; j < jend; ++j) {
      unsigned long long e = csr[j];
      unsigned int u = y1[(size_t)(e & 0xFFFFu) * 64 + lane];
      float w = __uint_as_float(((unsigned int)(e >> 32)) << 16);
      sx = fmaf(bflo(u), w, sx);
      sy = fmaf(bfhi(u), w, sy);
    }
    if (g == g0) {
      px += sx;
      py += sy;
    } else {
      atomicAdd(&Zb[(size_t)g * FDIM + 2 * lane], sx);
      atomicAdd(&Zb[(size_t)g * FDIM + 2 * lane + 1], sy);
    }
    node = rend;
  }
  ((float2*)Partials)[(size_t)wid * 64 + lane] = make_float2(px, py);
  if (lane == 0) Gid[wid] = g0;
}

// Reduce partials + Zb -> Z[g]; out[g] = Z@W2 + nodecount*b2.
__global__ __launch_bounds__(128) void k_poolzw2(
    const float* __restrict__ Partials, const int* __restrict__ Gid,
    const float* __restrict__ Zb, const int* __restrict__ gstart,
    const float* __restrict__ W2, const float* __restrict__ b2,
    float* __restrict__ out) {
  __shared__ float Zs[FDIM];
  int g = blockIdx.x, t = threadIdx.x;
  int s = gstart[g], e = gstart[g + 1];
  float acc = Zb[(size_t)g * FDIM + t];
  if (e > s) {
    int w0 = s / NPW, w1 = (e - 1) / NPW;
    for (int w = w0; w <= w1; ++w)
      if (Gid[w] == g) acc += Partials[(size_t)w * FDIM + t];
  }
  Zs[t] = acc;
  __syncthreads();
  float o = 0.f;
#pragma unroll 8
  for (int k = 0; k < FDIM; ++k) o = fmaf(Zs[k], W2[k * FDIM + t], o);
  out[(size_t)g * FDIM + t] = o + (float)(e - s) * b2[t];
}

extern "C" void kernel_launch(void* const* d_in, const int* in_sizes, int n_in,
                              void* d_out, int out_size, void* d_ws,
                              size_t ws_size, hipStream_t stream) {
  const int* x_type = (const int*)d_in[0];
  const int* edge_index = (const int*)d_in[1];
  const int* batch = (const int*)d_in[2];
  const float* emb = (const float*)d_in[3];
  const float* W1 = (const float*)d_in[4];
  const float* b1 = (const float*)d_in[5];
  const float* W2 = (const float*)d_in[6];
  const float* b2 = (const float*)d_in[7];
  float* out = (float*)d_out;

  const int* src = edge_index;
  const int* dst = edge_index + N_EDGES;

  char* p = (char*)d_ws;
  size_t off = 0;
  auto alloc = [&](size_t bytes) {
    void* r = p + off;
    off = (off + bytes + 255) & ~(size_t)255;
    return r;
  };
  float* dis = (float*)alloc(N_NODES * 4);
  int* row_ptr = (int*)alloc((N_NODES + 1) * 4);
  int* gstart = (int*)alloc((N_GRAPHS + 1) * 4);
  unsigned int* Hist = (unsigned int*)alloc((size_t)NBLK * NQUAD * 4);
  unsigned int* Cur = (unsigned int*)alloc((size_t)NBLK * NQUAD * 4);
  unsigned char* rank8 = (unsigned char*)alloc(N_EDGES);
  unsigned long long* csr =
      (unsigned long long*)alloc((size_t)N_EDGES * 8);
  unsigned short* T1 = (unsigned short*)alloc((size_t)NTYPES_PAD * FDIM * 2);
  unsigned int* y1 = (unsigned int*)alloc((size_t)N_NODES * 64 * 4);
  float* Partials = (float*)alloc((size_t)NW * FDIM * 4);
  int* Gid = (int*)alloc(NW * 4);
  float* Zb = (float*)alloc((size_t)N_GRAPHS * FDIM * 4);
  int* g_bsum = (int*)alloc(NSB * 4);
  int* g_done = (int*)alloc(4);
  (void)ws_size;

  k_hist<<<NBLK, 512, 0, stream>>>(dst, Hist, rank8, g_done);
  k_prep<<<NSB, 128, 0, stream>>>(Hist, batch, Cur, dis, row_ptr, Zb, gstart,
                                  g_bsum, g_done);
  k_fill2<<<(N_EDGES + 511) / 512, 512, 0, stream>>>(
      src, dst, x_type, row_ptr, Cur, rank8, dis, csr);
  k_embw<<<(NTYPES_PAD + 63) / 64, 256, 0, stream>>>(emb, W1, T1);
  k_agg1<<<(N_NODES * 64 + 255) / 256, 256, 0, stream>>>(
      x_type, T1, b1, row_ptr, csr, dis, y1);
  k_aggpool<<<(NW * 64 + 255) / 256, 256, 0, stream>>>(
      y1, row_ptr, csr, dis, batch, Partials, Gid, Zb);
  k_poolzw2<<<N_GRAPHS, 128, 0, stream>>>(Partials, Gid, Zb, gstart, W2, b2,
                                          out);
}